// Round 1
// baseline (504.118 us; speedup 1.0000x reference)
//
#include <hip/hip_runtime.h>
#include <hip/hip_bf16.h>

#define FIN 128
#define HC 256
#define H1 4
#define C1 64
#define OUT2 16

// ---------------- GEMM1: h1 = x @ W1  (N x 128) @ (128 x 256) ----------------
// block 256 threads, tile 64 rows x 256 cols, K=128 in steps of 32.
// micro-tile 8 rows x 8 cols per thread (cols = 2*(t&31) + 64j).
__global__ __launch_bounds__(256) void gemm1_kernel(
    const float* __restrict__ x, const float* __restrict__ W1,
    float* __restrict__ h1, int N)
{
    __shared__ float As[32][68];   // [k][row], padded
    __shared__ float Bs[32][260];  // [k][col], padded
    const int t = threadIdx.x;
    const int rb = blockIdx.x * 64;
    const int rg = t >> 5;          // 0..7 row-group
    const int cg = t & 31;          // col group
    const int r0 = rg * 8;

    float2 acc[8][4];
    #pragma unroll
    for (int i = 0; i < 8; i++)
        #pragma unroll
        for (int j = 0; j < 4; j++) acc[i][j] = make_float2(0.f, 0.f);

    for (int kb = 0; kb < FIN; kb += 32) {
        // A tile: 64 rows x 32 k; thread loads 8 floats of one row, stores transposed
        {
            int row = t >> 2;
            int k8 = (t & 3) * 8;
            int gr = rb + row;
            float4 v0 = make_float4(0,0,0,0), v1 = make_float4(0,0,0,0);
            if (gr < N) {
                v0 = *(const float4*)&x[(size_t)gr * FIN + kb + k8];
                v1 = *(const float4*)&x[(size_t)gr * FIN + kb + k8 + 4];
            }
            As[k8+0][row] = v0.x; As[k8+1][row] = v0.y; As[k8+2][row] = v0.z; As[k8+3][row] = v0.w;
            As[k8+4][row] = v1.x; As[k8+5][row] = v1.y; As[k8+6][row] = v1.z; As[k8+7][row] = v1.w;
        }
        // B tile: 32 k x 256 cols
        {
            int k = t >> 3;
            int c4 = (t & 7) * 4;
            #pragma unroll
            for (int j = 0; j < 8; j++) {
                float4 v = *(const float4*)&W1[(size_t)(kb + k) * HC + c4 + 32*j];
                *(float4*)&Bs[k][c4 + 32*j] = v;
            }
        }
        __syncthreads();
        #pragma unroll 4
        for (int k = 0; k < 32; k++) {
            float4 aA = *(const float4*)&As[k][r0];
            float4 aB = *(const float4*)&As[k][r0 + 4];
            float2 b[4];
            #pragma unroll
            for (int j = 0; j < 4; j++) b[j] = *(const float2*)&Bs[k][2*cg + 64*j];
            float av[8] = {aA.x, aA.y, aA.z, aA.w, aB.x, aB.y, aB.z, aB.w};
            #pragma unroll
            for (int i = 0; i < 8; i++) {
                #pragma unroll
                for (int j = 0; j < 4; j++) {
                    acc[i][j].x = fmaf(av[i], b[j].x, acc[i][j].x);
                    acc[i][j].y = fmaf(av[i], b[j].y, acc[i][j].y);
                }
            }
        }
        __syncthreads();
    }
    #pragma unroll
    for (int i = 0; i < 8; i++) {
        int gr = rb + r0 + i;
        if (gr < N) {
            #pragma unroll
            for (int j = 0; j < 4; j++)
                *(float2*)&h1[(size_t)gr * HC + 2*cg + 64*j] = acc[i][j];
        }
    }
}

// ------------- attention dots layer1: a_src[n][h], a_dst[n][h] -------------
// one wave per node; lane l owns h1 elements 4l..4l+3, head = l>>4
__global__ __launch_bounds__(256) void attdots1_kernel(
    const float* __restrict__ h1, const float* __restrict__ att_src,
    const float* __restrict__ att_dst, float* __restrict__ a_src,
    float* __restrict__ a_dst, int N)
{
    int wave = (int)((blockIdx.x * blockDim.x + threadIdx.x) >> 6);
    int l = threadIdx.x & 63;
    if (wave >= N) return;
    int h = l >> 4;
    int ci = 4 * (l & 15);
    float4 hv = *(const float4*)&h1[(size_t)wave * HC + 4*l];
    float4 asv = *(const float4*)&att_src[h * C1 + ci];
    float4 adv = *(const float4*)&att_dst[h * C1 + ci];
    float ps = hv.x*asv.x + hv.y*asv.y + hv.z*asv.z + hv.w*asv.w;
    float pd = hv.x*adv.x + hv.y*adv.y + hv.z*adv.z + hv.w*adv.w;
    #pragma unroll
    for (int off = 1; off < 16; off <<= 1) {
        ps += __shfl_xor(ps, off, 64);
        pd += __shfl_xor(pd, off, 64);
    }
    if ((l & 15) == 0) {
        a_src[wave * 4 + h] = ps;
        a_dst[wave * 4 + h] = pd;
    }
}

// ---------------- CSR build ----------------
__global__ __launch_bounds__(256) void count_kernel(
    const int* __restrict__ dst, int* __restrict__ counts, int E)
{
    int e = blockIdx.x * blockDim.x + threadIdx.x;
    if (e < E) atomicAdd(&counts[dst[e]], 1);
}

__global__ __launch_bounds__(1024) void scan_kernel(
    const int* __restrict__ counts, int* __restrict__ rowptr, int n)
{
    __shared__ int sm[1024];
    __shared__ int s_carry;
    int tid = threadIdx.x;
    if (tid == 0) s_carry = 0;
    __syncthreads();
    for (int base = 0; base < n; base += 1024) {
        int i = base + tid;
        int v = (i < n) ? counts[i] : 0;
        sm[tid] = v;
        __syncthreads();
        for (int off = 1; off < 1024; off <<= 1) {
            int tv = (tid >= off) ? sm[tid - off] : 0;
            __syncthreads();
            sm[tid] += tv;
            __syncthreads();
        }
        int incl = sm[tid];
        int carry = s_carry;
        if (i < n) rowptr[i] = carry + incl - v;
        __syncthreads();
        if (tid == 1023) s_carry = carry + incl;
        __syncthreads();
    }
    if (tid == 0) rowptr[n] = s_carry;
}

__global__ __launch_bounds__(256) void scatter_kernel(
    const int* __restrict__ dst, const int* __restrict__ rowptr,
    int* __restrict__ cursor, int* __restrict__ eids, int E)
{
    int e = blockIdx.x * blockDim.x + threadIdx.x;
    if (e >= E) return;
    int d = dst[e];
    int pos = rowptr[d] + atomicAdd(&cursor[d], 1);
    eids[pos] = e;
}

// sort each segment ascending by edge id -> bit-deterministic accumulation order
__global__ __launch_bounds__(256) void sortseg_kernel(
    const int* __restrict__ rowptr, int* __restrict__ eids, int N)
{
    int n = blockIdx.x * blockDim.x + threadIdx.x;
    if (n >= N) return;
    int s = rowptr[n], e = rowptr[n + 1];
    for (int i = s + 1; i < e; i++) {
        int v = eids[i];
        int j = i - 1;
        while (j >= s && eids[j] > v) { eids[j + 1] = eids[j]; j--; }
        eids[j + 1] = v;
    }
}

// ------------- edge weights layer1: w = exp(leaky(a_src[s]+a_dst[d])) -------------
__global__ __launch_bounds__(256) void edgew1_kernel(
    const int* __restrict__ src, const int* __restrict__ dst,
    const float* __restrict__ a_src, const float* __restrict__ a_dst,
    float* __restrict__ w1e, int E)
{
    int e = blockIdx.x * blockDim.x + threadIdx.x;
    if (e >= E) return;
    int s = src[e], d = dst[e];
    float4 av = *(const float4*)&a_src[(size_t)s * 4];
    float4 bv = *(const float4*)&a_dst[(size_t)d * 4];
    float4 o;
    float v;
    v = av.x + bv.x; v = v > 0.f ? v : 0.2f * v; o.x = expf(v);
    v = av.y + bv.y; v = v > 0.f ? v : 0.2f * v; o.y = expf(v);
    v = av.z + bv.z; v = v > 0.f ? v : 0.2f * v; o.z = expf(v);
    v = av.w + bv.w; v = v > 0.f ? v : 0.2f * v; o.w = expf(v);
    *(float4*)&w1e[(size_t)e * 4] = o;
}

// ------------- aggregate layer1 + bias + relu -------------
// one wave per node; lane l owns out elements 4l..4l+3 (head h=l>>4)
__global__ __launch_bounds__(256) void agg1_kernel(
    const float* __restrict__ h1, const float* __restrict__ w1e,
    const int* __restrict__ eids, const int* __restrict__ rowptr,
    const int* __restrict__ src, const float* __restrict__ b1,
    float* __restrict__ out1, int N)
{
    int wave = (int)((blockIdx.x * blockDim.x + threadIdx.x) >> 6);
    int l = threadIdx.x & 63;
    if (wave >= N) return;
    int rs = rowptr[wave], re = rowptr[wave + 1];
    int h = l >> 4;
    float4 acc = make_float4(0, 0, 0, 0);
    float sw = 0.f;
    for (int p = rs; p < re; p++) {
        int eid = eids[p];
        int sn = src[eid];
        float wv = w1e[(size_t)eid * 4 + h];
        float4 hv = *(const float4*)&h1[(size_t)sn * HC + 4*l];
        acc.x = fmaf(wv, hv.x, acc.x);
        acc.y = fmaf(wv, hv.y, acc.y);
        acc.z = fmaf(wv, hv.z, acc.z);
        acc.w = fmaf(wv, hv.w, acc.w);
        sw += wv;
    }
    float inv = 1.f / (sw + 1e-16f);
    float4 bv = *(const float4*)&b1[4*l];
    float4 o;
    o.x = fmaxf(acc.x * inv + bv.x, 0.f);
    o.y = fmaxf(acc.y * inv + bv.y, 0.f);
    o.z = fmaxf(acc.z * inv + bv.z, 0.f);
    o.w = fmaxf(acc.w * inv + bv.w, 0.f);
    *(float4*)&out1[(size_t)wave * HC + 4*l] = o;
}

// ------------- GEMM2 (N x 256)@(256 x 16) fused with attention dots -------------
__global__ __launch_bounds__(256) void gemm2_kernel(
    const float* __restrict__ out1, const float* __restrict__ W2,
    const float* __restrict__ att_src2, const float* __restrict__ att_dst2,
    float* __restrict__ h2, float* __restrict__ a_src2, float* __restrict__ a_dst2,
    int N)
{
    __shared__ float xs[16][260];
    __shared__ float W2s[256 * 16];
    int t = threadIdx.x;
    int rb = blockIdx.x * 16;
    {
        int r = t >> 4;
        int k0 = (t & 15) * 4;
        int gr = rb + r;
        #pragma unroll
        for (int j = 0; j < 4; j++) {
            float4 v = make_float4(0,0,0,0);
            if (gr < N) v = *(const float4*)&out1[(size_t)gr * HC + k0 + 64*j];
            *(float4*)&xs[r][k0 + 64*j] = v;
        }
    }
    {
        #pragma unroll
        for (int j = 0; j < 4; j++) {
            float4 v = ((const float4*)W2)[j * 256 + t];
            ((float4*)W2s)[j * 256 + t] = v;
        }
    }
    __syncthreads();
    int r = t >> 4, c = t & 15;
    float acc = 0.f;
    #pragma unroll 8
    for (int k = 0; k < 256; k++)
        acc = fmaf(xs[r][k], W2s[k * 16 + c], acc);
    int gr = rb + r;
    float ps = acc * att_src2[c];
    float pd = acc * att_dst2[c];
    #pragma unroll
    for (int off = 1; off < 16; off <<= 1) {
        ps += __shfl_xor(ps, off, 64);
        pd += __shfl_xor(pd, off, 64);
    }
    if (gr < N) {
        h2[(size_t)gr * OUT2 + c] = acc;
        if (c == 0) { a_src2[gr] = ps; a_dst2[gr] = pd; }
    }
}

// ------------- edge weights layer2 -------------
__global__ __launch_bounds__(256) void edgew2_kernel(
    const int* __restrict__ src, const int* __restrict__ dst,
    const float* __restrict__ a_src, const float* __restrict__ a_dst,
    float* __restrict__ w2e, int E)
{
    int e = blockIdx.x * blockDim.x + threadIdx.x;
    if (e >= E) return;
    float v = a_src[src[e]] + a_dst[dst[e]];
    v = v > 0.f ? v : 0.2f * v;
    w2e[e] = expf(v);
}

// ------------- aggregate layer2 + bias -> out -------------
// one wave per node; lane = (group g=l>>4 handles every 4th edge, c=l&15)
__global__ __launch_bounds__(256) void agg2_kernel(
    const float* __restrict__ h2, const float* __restrict__ w2e,
    const int* __restrict__ eids, const int* __restrict__ rowptr,
    const int* __restrict__ src, const float* __restrict__ b2,
    float* __restrict__ out, int N)
{
    int wave = (int)((blockIdx.x * blockDim.x + threadIdx.x) >> 6);
    int l = threadIdx.x & 63;
    if (wave >= N) return;
    int rs = rowptr[wave], re = rowptr[wave + 1];
    int g = l >> 4, c = l & 15;
    float acc = 0.f, sw = 0.f;
    for (int p = rs + g; p < re; p += 4) {
        int eid = eids[p];
        int sn = src[eid];
        float wv = w2e[eid];
        acc = fmaf(wv, h2[(size_t)sn * OUT2 + c], acc);
        sw += wv;
    }
    acc += __shfl_xor(acc, 16, 64);
    acc += __shfl_xor(acc, 32, 64);
    sw += __shfl_xor(sw, 16, 64);
    sw += __shfl_xor(sw, 32, 64);
    if (l < 16)
        out[(size_t)wave * OUT2 + l] = acc / (sw + 1e-16f) + b2[l];
}

extern "C" void kernel_launch(void* const* d_in, const int* in_sizes, int n_in,
                              void* d_out, int out_size, void* d_ws, size_t ws_size,
                              hipStream_t stream)
{
    const float* x        = (const float*)d_in[0];
    const int*   ei       = (const int*)d_in[1];
    const float* W1       = (const float*)d_in[2];
    const float* att_src1 = (const float*)d_in[3];
    const float* att_dst1 = (const float*)d_in[4];
    const float* b1       = (const float*)d_in[5];
    const float* W2       = (const float*)d_in[6];
    const float* att_src2 = (const float*)d_in[7];
    const float* att_dst2 = (const float*)d_in[8];
    const float* b2       = (const float*)d_in[9];
    float* out = (float*)d_out;

    const int N = in_sizes[0] / FIN;
    const int E = in_sizes[1] / 2;
    const int* srcv = ei;
    const int* dstv = ei + E;

    float* w = (float*)d_ws;
    float* h1      = w; w += (size_t)N * HC;
    float* out1    = w; w += (size_t)N * HC;
    float* h2      = w; w += (size_t)N * OUT2;
    float* a_src1v = w; w += (size_t)N * 4;
    float* a_dst1v = w; w += (size_t)N * 4;
    float* a_src2v = w; w += N;
    float* a_dst2v = w; w += N;
    float* w1e     = w; w += (size_t)E * 4;
    float* w2e     = w; w += E;
    int* counts = (int*)w;
    int* cursor = counts + N;
    int* eids   = cursor + N;
    int* rowptr = eids + E;   // N+1 entries

    hipMemsetAsync(counts, 0, sizeof(int) * 2 * (size_t)N, stream);

    gemm1_kernel<<<(N + 63) / 64, 256, 0, stream>>>(x, W1, h1, N);
    attdots1_kernel<<<(N + 3) / 4, 256, 0, stream>>>(h1, att_src1, att_dst1, a_src1v, a_dst1v, N);
    count_kernel<<<(E + 255) / 256, 256, 0, stream>>>(dstv, counts, E);
    scan_kernel<<<1, 1024, 0, stream>>>(counts, rowptr, N);
    scatter_kernel<<<(E + 255) / 256, 256, 0, stream>>>(dstv, rowptr, cursor, eids, E);
    sortseg_kernel<<<(N + 255) / 256, 256, 0, stream>>>(rowptr, eids, N);
    edgew1_kernel<<<(E + 255) / 256, 256, 0, stream>>>(srcv, dstv, a_src1v, a_dst1v, w1e, E);
    agg1_kernel<<<(N + 3) / 4, 256, 0, stream>>>(h1, w1e, eids, rowptr, srcv, b1, out1, N);
    gemm2_kernel<<<(N + 15) / 16, 256, 0, stream>>>(out1, W2, att_src2, att_dst2, h2, a_src2v, a_dst2v, N);
    edgew2_kernel<<<(E + 255) / 256, 256, 0, stream>>>(srcv, dstv, a_src2v, a_dst2v, w2e, E);
    agg2_kernel<<<(N + 3) / 4, 256, 0, stream>>>(h2, w2e, eids, rowptr, srcv, b2, out, N);
}

// Round 2
// 306.271 us; speedup vs baseline: 1.6460x; 1.6460x over previous
//
#include <hip/hip_runtime.h>
#include <hip/hip_bf16.h>

#define FIN 128
#define HC 256
#define H1 4
#define C1 64
#define OUT2 16

__device__ inline float bf2f(unsigned short u) {
    union { unsigned int i; float f; } v; v.i = ((unsigned int)u) << 16; return v.f;
}
__device__ inline unsigned short f2bf(float f) {
    union { float f; unsigned int i; } v; v.f = f;
    unsigned int i = v.i;
    return (unsigned short)((i + 0x7FFFu + ((i >> 16) & 1u)) >> 16);
}
__device__ inline unsigned int pack2(float a, float b) {
    return (unsigned int)f2bf(a) | ((unsigned int)f2bf(b) << 16);
}

// ---------------- GEMM1: h1 = x @ W1  (N x 128) @ (128 x 256), bf16 out ----------------
__global__ __launch_bounds__(256) void gemm1_kernel(
    const float* __restrict__ x, const float* __restrict__ W1,
    unsigned short* __restrict__ h1, int N)
{
    __shared__ float As[32][68];   // [k][row], padded
    __shared__ float Bs[32][260];  // [k][col], padded
    const int t = threadIdx.x;
    const int rb = blockIdx.x * 64;
    const int rg = t >> 5;          // 0..7 row-group
    const int cg = t & 31;          // col group
    const int r0 = rg * 8;

    float2 acc[8][4];
    #pragma unroll
    for (int i = 0; i < 8; i++)
        #pragma unroll
        for (int j = 0; j < 4; j++) acc[i][j] = make_float2(0.f, 0.f);

    for (int kb = 0; kb < FIN; kb += 32) {
        {
            int row = t >> 2;
            int k8 = (t & 3) * 8;
            int gr = rb + row;
            float4 v0 = make_float4(0,0,0,0), v1 = make_float4(0,0,0,0);
            if (gr < N) {
                v0 = *(const float4*)&x[(size_t)gr * FIN + kb + k8];
                v1 = *(const float4*)&x[(size_t)gr * FIN + kb + k8 + 4];
            }
            As[k8+0][row] = v0.x; As[k8+1][row] = v0.y; As[k8+2][row] = v0.z; As[k8+3][row] = v0.w;
            As[k8+4][row] = v1.x; As[k8+5][row] = v1.y; As[k8+6][row] = v1.z; As[k8+7][row] = v1.w;
        }
        {
            int k = t >> 3;
            int c4 = (t & 7) * 4;
            #pragma unroll
            for (int j = 0; j < 8; j++) {
                float4 v = *(const float4*)&W1[(size_t)(kb + k) * HC + c4 + 32*j];
                *(float4*)&Bs[k][c4 + 32*j] = v;
            }
        }
        __syncthreads();
        #pragma unroll 4
        for (int k = 0; k < 32; k++) {
            float4 aA = *(const float4*)&As[k][r0];
            float4 aB = *(const float4*)&As[k][r0 + 4];
            float2 b[4];
            #pragma unroll
            for (int j = 0; j < 4; j++) b[j] = *(const float2*)&Bs[k][2*cg + 64*j];
            float av[8] = {aA.x, aA.y, aA.z, aA.w, aB.x, aB.y, aB.z, aB.w};
            #pragma unroll
            for (int i = 0; i < 8; i++) {
                #pragma unroll
                for (int j = 0; j < 4; j++) {
                    acc[i][j].x = fmaf(av[i], b[j].x, acc[i][j].x);
                    acc[i][j].y = fmaf(av[i], b[j].y, acc[i][j].y);
                }
            }
        }
        __syncthreads();
    }
    #pragma unroll
    for (int i = 0; i < 8; i++) {
        int gr = rb + r0 + i;
        if (gr < N) {
            unsigned int* hp = (unsigned int*)&h1[(size_t)gr * HC];
            #pragma unroll
            for (int j = 0; j < 4; j++)
                hp[cg + 32*j] = pack2(acc[i][j].x, acc[i][j].y);
        }
    }
}

// ------------- attention dots layer1 (bf16 h1) -------------
__global__ __launch_bounds__(256) void attdots1_kernel(
    const unsigned short* __restrict__ h1, const float* __restrict__ att_src,
    const float* __restrict__ att_dst, float* __restrict__ a_src,
    float* __restrict__ a_dst, int N)
{
    int wave = (int)((blockIdx.x * blockDim.x + threadIdx.x) >> 6);
    int l = threadIdx.x & 63;
    if (wave >= N) return;
    int h = l >> 4;
    int ci = 4 * (l & 15);
    uint2 hv = *(const uint2*)&h1[(size_t)wave * HC + 4*l];
    float f0 = bf2f((unsigned short)(hv.x & 0xffff));
    float f1 = bf2f((unsigned short)(hv.x >> 16));
    float f2 = bf2f((unsigned short)(hv.y & 0xffff));
    float f3 = bf2f((unsigned short)(hv.y >> 16));
    float4 asv = *(const float4*)&att_src[h * C1 + ci];
    float4 adv = *(const float4*)&att_dst[h * C1 + ci];
    float ps = f0*asv.x + f1*asv.y + f2*asv.z + f3*asv.w;
    float pd = f0*adv.x + f1*adv.y + f2*adv.z + f3*adv.w;
    #pragma unroll
    for (int off = 1; off < 16; off <<= 1) {
        ps += __shfl_xor(ps, off, 64);
        pd += __shfl_xor(pd, off, 64);
    }
    if ((l & 15) == 0) {
        a_src[wave * 4 + h] = ps;
        a_dst[wave * 4 + h] = pd;
    }
}

// ---------------- CSR build ----------------
__global__ __launch_bounds__(256) void count_kernel(
    const int* __restrict__ dst, int* __restrict__ counts, int E)
{
    int e = blockIdx.x * blockDim.x + threadIdx.x;
    if (e < E) atomicAdd(&counts[dst[e]], 1);
}

__global__ __launch_bounds__(1024) void scan1_kernel(
    const int* __restrict__ counts, int* __restrict__ rowptr,
    int* __restrict__ bsum, int n)
{
    __shared__ int sm[1024];
    int tid = threadIdx.x;
    int i = blockIdx.x * 1024 + tid;
    int v = (i < n) ? counts[i] : 0;
    sm[tid] = v;
    __syncthreads();
    for (int off = 1; off < 1024; off <<= 1) {
        int tv = (tid >= off) ? sm[tid - off] : 0;
        __syncthreads();
        sm[tid] += tv;
        __syncthreads();
    }
    if (i < n) rowptr[i] = sm[tid] - v;     // block-local exclusive
    if (tid == 1023) bsum[blockIdx.x] = sm[1023];
}

__global__ __launch_bounds__(1024) void scan2_kernel(
    int* __restrict__ bsum, int* __restrict__ rowptr, int nb, int N, int E)
{
    __shared__ int sm[1024];
    int tid = threadIdx.x;
    int v = (tid < nb) ? bsum[tid] : 0;
    sm[tid] = v;
    __syncthreads();
    for (int off = 1; off < 1024; off <<= 1) {
        int tv = (tid >= off) ? sm[tid - off] : 0;
        __syncthreads();
        sm[tid] += tv;
        __syncthreads();
    }
    if (tid < nb) bsum[tid] = sm[tid] - v;  // exclusive block offsets
    if (tid == 0) rowptr[N] = E;
}

__global__ __launch_bounds__(1024) void scan3_kernel(
    int* __restrict__ rowptr, const int* __restrict__ bsum, int n)
{
    int i = blockIdx.x * 1024 + threadIdx.x;
    if (i < n) rowptr[i] += bsum[blockIdx.x];
}

// scatter: store SOURCE NODE directly (removes one indirection in agg loops)
__global__ __launch_bounds__(256) void scatter_kernel(
    const int* __restrict__ src, const int* __restrict__ dst,
    const int* __restrict__ rowptr, int* __restrict__ cursor,
    int* __restrict__ csr_src, int E)
{
    int e = blockIdx.x * blockDim.x + threadIdx.x;
    if (e >= E) return;
    int d = dst[e];
    int pos = rowptr[d] + atomicAdd(&cursor[d], 1);
    csr_src[pos] = src[e];
}

// ------------- aggregate layer1 (fused edge weights) + bias + relu, bf16 out -------------
__global__ __launch_bounds__(256) void agg1_kernel(
    const unsigned short* __restrict__ h1,
    const float* __restrict__ a_src, const float* __restrict__ a_dst,
    const int* __restrict__ csr_src, const int* __restrict__ rowptr,
    const float* __restrict__ b1, unsigned short* __restrict__ out1, int N)
{
    int wave = (int)((blockIdx.x * blockDim.x + threadIdx.x) >> 6);
    int l = threadIdx.x & 63;
    if (wave >= N) return;
    int rs = rowptr[wave], re = rowptr[wave + 1];
    int h = l >> 4;
    float ad = a_dst[wave * 4 + h];
    float4 acc = make_float4(0, 0, 0, 0);
    float sw = 0.f;
    for (int p = rs; p < re; p++) {
        int sn = csr_src[p];
        float e = a_src[sn * 4 + h] + ad;
        e = e > 0.f ? e : 0.2f * e;
        float wv = __expf(e);
        uint2 hv = *(const uint2*)&h1[(size_t)sn * HC + 4*l];
        acc.x = fmaf(wv, bf2f((unsigned short)(hv.x & 0xffff)), acc.x);
        acc.y = fmaf(wv, bf2f((unsigned short)(hv.x >> 16)), acc.y);
        acc.z = fmaf(wv, bf2f((unsigned short)(hv.y & 0xffff)), acc.z);
        acc.w = fmaf(wv, bf2f((unsigned short)(hv.y >> 16)), acc.w);
        sw += wv;
    }
    float inv = 1.f / (sw + 1e-16f);
    float4 bv = *(const float4*)&b1[4*l];
    float o0 = fmaxf(acc.x * inv + bv.x, 0.f);
    float o1 = fmaxf(acc.y * inv + bv.y, 0.f);
    float o2 = fmaxf(acc.z * inv + bv.z, 0.f);
    float o3 = fmaxf(acc.w * inv + bv.w, 0.f);
    unsigned int* op = (unsigned int*)&out1[(size_t)wave * HC + 4*l];
    op[0] = pack2(o0, o1);
    op[1] = pack2(o2, o3);
}

// ------------- GEMM2 (N x 256)@(256 x 16) fused with attention dots, bf16 in -------------
__global__ __launch_bounds__(256) void gemm2_kernel(
    const unsigned short* __restrict__ out1, const float* __restrict__ W2,
    const float* __restrict__ att_src2, const float* __restrict__ att_dst2,
    float* __restrict__ h2, float* __restrict__ a_src2, float* __restrict__ a_dst2,
    int N)
{
    __shared__ float xs[16][260];
    __shared__ float W2s[256 * 16];
    int t = threadIdx.x;
    int rb = blockIdx.x * 16;
    {
        int r = t >> 4;
        int k0 = (t & 15) * 4;
        int gr = rb + r;
        #pragma unroll
        for (int j = 0; j < 4; j++) {
            uint2 v = make_uint2(0, 0);
            if (gr < N) v = *(const uint2*)&out1[(size_t)gr * HC + k0 + 64*j];
            xs[r][k0 + 64*j + 0] = bf2f((unsigned short)(v.x & 0xffff));
            xs[r][k0 + 64*j + 1] = bf2f((unsigned short)(v.x >> 16));
            xs[r][k0 + 64*j + 2] = bf2f((unsigned short)(v.y & 0xffff));
            xs[r][k0 + 64*j + 3] = bf2f((unsigned short)(v.y >> 16));
        }
    }
    {
        #pragma unroll
        for (int j = 0; j < 4; j++) {
            float4 v = ((const float4*)W2)[j * 256 + t];
            ((float4*)W2s)[j * 256 + t] = v;
        }
    }
    __syncthreads();
    int r = t >> 4, c = t & 15;
    float acc = 0.f;
    #pragma unroll 8
    for (int k = 0; k < 256; k++)
        acc = fmaf(xs[r][k], W2s[k * 16 + c], acc);
    int gr = rb + r;
    float ps = acc * att_src2[c];
    float pd = acc * att_dst2[c];
    #pragma unroll
    for (int off = 1; off < 16; off <<= 1) {
        ps += __shfl_xor(ps, off, 64);
        pd += __shfl_xor(pd, off, 64);
    }
    if (gr < N) {
        h2[(size_t)gr * OUT2 + c] = acc;
        if (c == 0) { a_src2[gr] = ps; a_dst2[gr] = pd; }
    }
}

// ------------- aggregate layer2 (fused edge weights) + bias -> out -------------
__global__ __launch_bounds__(256) void agg2_kernel(
    const float* __restrict__ h2,
    const float* __restrict__ a_src2, const float* __restrict__ a_dst2,
    const int* __restrict__ csr_src, const int* __restrict__ rowptr,
    const float* __restrict__ b2, float* __restrict__ out, int N)
{
    int wave = (int)((blockIdx.x * blockDim.x + threadIdx.x) >> 6);
    int l = threadIdx.x & 63;
    if (wave >= N) return;
    int rs = rowptr[wave], re = rowptr[wave + 1];
    int g = l >> 4, c = l & 15;
    float ad = a_dst2[wave];
    float acc = 0.f, sw = 0.f;
    for (int p = rs + g; p < re; p += 4) {
        int sn = csr_src[p];
        float e = a_src2[sn] + ad;
        e = e > 0.f ? e : 0.2f * e;
        float wv = __expf(e);
        acc = fmaf(wv, h2[(size_t)sn * OUT2 + c], acc);
        sw += wv;
    }
    acc += __shfl_xor(acc, 16, 64);
    acc += __shfl_xor(acc, 32, 64);
    sw += __shfl_xor(sw, 16, 64);
    sw += __shfl_xor(sw, 32, 64);
    if (l < 16)
        out[(size_t)wave * OUT2 + l] = acc / (sw + 1e-16f) + b2[l];
}

extern "C" void kernel_launch(void* const* d_in, const int* in_sizes, int n_in,
                              void* d_out, int out_size, void* d_ws, size_t ws_size,
                              hipStream_t stream)
{
    const float* x        = (const float*)d_in[0];
    const int*   ei       = (const int*)d_in[1];
    const float* W1       = (const float*)d_in[2];
    const float* att_src1 = (const float*)d_in[3];
    const float* att_dst1 = (const float*)d_in[4];
    const float* b1       = (const float*)d_in[5];
    const float* W2       = (const float*)d_in[6];
    const float* att_src2 = (const float*)d_in[7];
    const float* att_dst2 = (const float*)d_in[8];
    const float* b2       = (const float*)d_in[9];
    float* out = (float*)d_out;

    const int N = in_sizes[0] / FIN;
    const int E = in_sizes[1] / 2;
    const int* srcv = ei;
    const int* dstv = ei + E;

    char* base = (char*)d_ws;
    unsigned short* h1   = (unsigned short*)base; base += (size_t)N * HC * 2;
    unsigned short* out1 = (unsigned short*)base; base += (size_t)N * HC * 2;
    float* h2      = (float*)base; base += (size_t)N * OUT2 * 4;
    float* a_src1v = (float*)base; base += (size_t)N * 4 * 4;
    float* a_dst1v = (float*)base; base += (size_t)N * 4 * 4;
    float* a_src2v = (float*)base; base += (size_t)N * 4;
    float* a_dst2v = (float*)base; base += (size_t)N * 4;
    int* counts  = (int*)base; base += (size_t)N * 4;
    int* cursor  = (int*)base; base += (size_t)N * 4;
    int* csr_src = (int*)base; base += (size_t)E * 4;
    int* rowptr  = (int*)base; base += (size_t)(N + 1) * 4;
    int* bsum    = (int*)base; base += 1024 * 4;

    const int nb = (N + 1023) / 1024;

    hipMemsetAsync(counts, 0, sizeof(int) * 2 * (size_t)N, stream);

    gemm1_kernel<<<(N + 63) / 64, 256, 0, stream>>>(x, W1, h1, N);
    attdots1_kernel<<<(N + 3) / 4, 256, 0, stream>>>(h1, att_src1, att_dst1, a_src1v, a_dst1v, N);
    count_kernel<<<(E + 255) / 256, 256, 0, stream>>>(dstv, counts, E);
    scan1_kernel<<<nb, 1024, 0, stream>>>(counts, rowptr, bsum, N);
    scan2_kernel<<<1, 1024, 0, stream>>>(bsum, rowptr, nb, N, E);
    scan3_kernel<<<nb, 1024, 0, stream>>>(rowptr, bsum, N);
    scatter_kernel<<<(E + 255) / 256, 256, 0, stream>>>(srcv, dstv, rowptr, cursor, csr_src, E);
    agg1_kernel<<<(N + 3) / 4, 256, 0, stream>>>(h1, a_src1v, a_dst1v, csr_src, rowptr, b1, out1, N);
    gemm2_kernel<<<(N + 15) / 16, 256, 0, stream>>>(out1, W2, att_src2, att_dst2, h2, a_src2v, a_dst2v, N);
    agg2_kernel<<<(N + 3) / 4, 256, 0, stream>>>(h2, a_src2v, a_dst2v, csr_src, rowptr, b2, out, N);
}

// Round 3
// 267.783 us; speedup vs baseline: 1.8826x; 1.1437x over previous
//
#include <hip/hip_runtime.h>
#include <hip/hip_bf16.h>

#define FIN 128
#define HC 256
#define H1 4
#define C1 64
#define OUT2 16

__device__ inline float bf2f(unsigned short u) {
    union { unsigned int i; float f; } v; v.i = ((unsigned int)u) << 16; return v.f;
}
__device__ inline unsigned short f2bf(float f) {
    union { float f; unsigned int i; } v; v.f = f;
    unsigned int i = v.i;
    return (unsigned short)((i + 0x7FFFu + ((i >> 16) & 1u)) >> 16);
}
__device__ inline unsigned int pack2(float a, float b) {
    return (unsigned int)f2bf(a) | ((unsigned int)f2bf(b) << 16);
}

// ---------------- GEMM1: h1 = x @ W1  (N x 128) @ (128 x 256), bf16 out ----------------
__global__ __launch_bounds__(256) void gemm1_kernel(
    const float* __restrict__ x, const float* __restrict__ W1,
    unsigned short* __restrict__ h1, int N)
{
    __shared__ float As[32][68];   // [k][row], padded
    __shared__ float Bs[32][260];  // [k][col], padded
    const int t = threadIdx.x;
    const int rb = blockIdx.x * 64;
    const int rg = t >> 5;          // 0..7 row-group
    const int cg = t & 31;          // col group
    const int r0 = rg * 8;

    float2 acc[8][4];
    #pragma unroll
    for (int i = 0; i < 8; i++)
        #pragma unroll
        for (int j = 0; j < 4; j++) acc[i][j] = make_float2(0.f, 0.f);

    for (int kb = 0; kb < FIN; kb += 32) {
        {
            int row = t >> 2;
            int k8 = (t & 3) * 8;
            int gr = rb + row;
            float4 v0 = make_float4(0,0,0,0), v1 = make_float4(0,0,0,0);
            if (gr < N) {
                v0 = *(const float4*)&x[(size_t)gr * FIN + kb + k8];
                v1 = *(const float4*)&x[(size_t)gr * FIN + kb + k8 + 4];
            }
            As[k8+0][row] = v0.x; As[k8+1][row] = v0.y; As[k8+2][row] = v0.z; As[k8+3][row] = v0.w;
            As[k8+4][row] = v1.x; As[k8+5][row] = v1.y; As[k8+6][row] = v1.z; As[k8+7][row] = v1.w;
        }
        {
            int k = t >> 3;
            int c4 = (t & 7) * 4;
            #pragma unroll
            for (int j = 0; j < 8; j++) {
                float4 v = *(const float4*)&W1[(size_t)(kb + k) * HC + c4 + 32*j];
                *(float4*)&Bs[k][c4 + 32*j] = v;
            }
        }
        __syncthreads();
        #pragma unroll 4
        for (int k = 0; k < 32; k++) {
            float4 aA = *(const float4*)&As[k][r0];
            float4 aB = *(const float4*)&As[k][r0 + 4];
            float2 b[4];
            #pragma unroll
            for (int j = 0; j < 4; j++) b[j] = *(const float2*)&Bs[k][2*cg + 64*j];
            float av[8] = {aA.x, aA.y, aA.z, aA.w, aB.x, aB.y, aB.z, aB.w};
            #pragma unroll
            for (int i = 0; i < 8; i++) {
                #pragma unroll
                for (int j = 0; j < 4; j++) {
                    acc[i][j].x = fmaf(av[i], b[j].x, acc[i][j].x);
                    acc[i][j].y = fmaf(av[i], b[j].y, acc[i][j].y);
                }
            }
        }
        __syncthreads();
    }
    #pragma unroll
    for (int i = 0; i < 8; i++) {
        int gr = rb + r0 + i;
        if (gr < N) {
            unsigned int* hp = (unsigned int*)&h1[(size_t)gr * HC];
            #pragma unroll
            for (int j = 0; j < 4; j++)
                hp[cg + 32*j] = pack2(acc[i][j].x, acc[i][j].y);
        }
    }
}

// ------------- attention dots layer1 (bf16 h1) -------------
__global__ __launch_bounds__(256) void attdots1_kernel(
    const unsigned short* __restrict__ h1, const float* __restrict__ att_src,
    const float* __restrict__ att_dst, float* __restrict__ a_src,
    float* __restrict__ a_dst, int N)
{
    int wave = (int)((blockIdx.x * blockDim.x + threadIdx.x) >> 6);
    int l = threadIdx.x & 63;
    if (wave >= N) return;
    int h = l >> 4;
    int ci = 4 * (l & 15);
    uint2 hv = *(const uint2*)&h1[(size_t)wave * HC + 4*l];
    float f0 = bf2f((unsigned short)(hv.x & 0xffff));
    float f1 = bf2f((unsigned short)(hv.x >> 16));
    float f2 = bf2f((unsigned short)(hv.y & 0xffff));
    float f3 = bf2f((unsigned short)(hv.y >> 16));
    float4 asv = *(const float4*)&att_src[h * C1 + ci];
    float4 adv = *(const float4*)&att_dst[h * C1 + ci];
    float ps = f0*asv.x + f1*asv.y + f2*asv.z + f3*asv.w;
    float pd = f0*adv.x + f1*adv.y + f2*adv.z + f3*adv.w;
    #pragma unroll
    for (int off = 1; off < 16; off <<= 1) {
        ps += __shfl_xor(ps, off, 64);
        pd += __shfl_xor(pd, off, 64);
    }
    if ((l & 15) == 0) {
        a_src[wave * 4 + h] = ps;
        a_dst[wave * 4 + h] = pd;
    }
}

// ---------------- CSR build ----------------
__global__ __launch_bounds__(256) void count_kernel(
    const int* __restrict__ dst, int* __restrict__ counts, int E)
{
    int e = blockIdx.x * blockDim.x + threadIdx.x;
    if (e < E) atomicAdd(&counts[dst[e]], 1);
}

__global__ __launch_bounds__(1024) void scan1_kernel(
    const int* __restrict__ counts, int* __restrict__ rowptr,
    int* __restrict__ bsum, int n)
{
    __shared__ int sm[1024];
    int tid = threadIdx.x;
    int i = blockIdx.x * 1024 + tid;
    int v = (i < n) ? counts[i] : 0;
    sm[tid] = v;
    __syncthreads();
    for (int off = 1; off < 1024; off <<= 1) {
        int tv = (tid >= off) ? sm[tid - off] : 0;
        __syncthreads();
        sm[tid] += tv;
        __syncthreads();
    }
    if (i < n) rowptr[i] = sm[tid] - v;     // block-local exclusive
    if (tid == 1023) bsum[blockIdx.x] = sm[1023];
}

__global__ __launch_bounds__(1024) void scan2_kernel(
    int* __restrict__ bsum, int* __restrict__ rowptr, int nb, int N, int E)
{
    __shared__ int sm[1024];
    int tid = threadIdx.x;
    int v = (tid < nb) ? bsum[tid] : 0;
    sm[tid] = v;
    __syncthreads();
    for (int off = 1; off < 1024; off <<= 1) {
        int tv = (tid >= off) ? sm[tid - off] : 0;
        __syncthreads();
        sm[tid] += tv;
        __syncthreads();
    }
    if (tid < nb) bsum[tid] = sm[tid] - v;  // exclusive block offsets
    if (tid == 0) rowptr[N] = E;
}

__global__ __launch_bounds__(1024) void scan3_kernel(
    int* __restrict__ rowptr, const int* __restrict__ bsum, int n)
{
    int i = blockIdx.x * 1024 + threadIdx.x;
    if (i < n) rowptr[i] += bsum[blockIdx.x];
}

// scatter: place src node, dst node, and layer-1 per-head edge weights at CSR position
__global__ __launch_bounds__(256) void scatter_kernel(
    const int* __restrict__ src, const int* __restrict__ dst,
    const int* __restrict__ rowptr, int* __restrict__ cursor,
    const float* __restrict__ a_src, const float* __restrict__ a_dst,
    int* __restrict__ csr_src, int* __restrict__ csr_dst,
    float4* __restrict__ csr_w, int E)
{
    int e = blockIdx.x * blockDim.x + threadIdx.x;
    if (e >= E) return;
    int s = src[e], d = dst[e];
    int pos = rowptr[d] + atomicAdd(&cursor[d], 1);
    csr_src[pos] = s;
    csr_dst[pos] = d;
    float4 av = *(const float4*)&a_src[(size_t)s * 4];
    float4 bv = *(const float4*)&a_dst[(size_t)d * 4];
    float4 o; float v;
    v = av.x + bv.x; v = v > 0.f ? v : 0.2f * v; o.x = __expf(v);
    v = av.y + bv.y; v = v > 0.f ? v : 0.2f * v; o.y = __expf(v);
    v = av.z + bv.z; v = v > 0.f ? v : 0.2f * v; o.z = __expf(v);
    v = av.w + bv.w; v = v > 0.f ? v : 0.2f * v; o.w = __expf(v);
    csr_w[pos] = o;
}

// ------------- aggregate layer1 + bias + relu, bf16 out -------------
// one wave per node; lane l owns out elements 4l..4l+3 (head h=l>>4)
// uniform (scalar) loads for csr_src/csr_w; unroll x4 for gather MLP
__global__ __launch_bounds__(256) void agg1_kernel(
    const unsigned short* __restrict__ h1,
    const int* __restrict__ csr_src, const float4* __restrict__ csr_w,
    const int* __restrict__ rowptr,
    const float* __restrict__ b1, unsigned short* __restrict__ out1, int N)
{
    int wave = (int)((blockIdx.x * blockDim.x + threadIdx.x) >> 6);
    if (wave >= N) return;
    int node = __builtin_amdgcn_readfirstlane(wave);
    int l = threadIdx.x & 63;
    int h = l >> 4;
    int rs = rowptr[node], re = rowptr[node + 1];
    float a0 = 0.f, a1 = 0.f, a2 = 0.f, a3 = 0.f, sw = 0.f;
    int p = rs;
    #define GETW(w4) ((h == 0) ? (w4).x : (h == 1) ? (w4).y : (h == 2) ? (w4).z : (w4).w)
    for (; p + 4 <= re; p += 4) {
        int sn0 = csr_src[p + 0], sn1 = csr_src[p + 1];
        int sn2 = csr_src[p + 2], sn3 = csr_src[p + 3];
        float4 w0 = csr_w[p + 0], w1 = csr_w[p + 1];
        float4 w2 = csr_w[p + 2], w3 = csr_w[p + 3];
        uint2 v0 = *(const uint2*)&h1[(size_t)sn0 * HC + 4 * l];
        uint2 v1 = *(const uint2*)&h1[(size_t)sn1 * HC + 4 * l];
        uint2 v2 = *(const uint2*)&h1[(size_t)sn2 * HC + 4 * l];
        uint2 v3 = *(const uint2*)&h1[(size_t)sn3 * HC + 4 * l];
        float wv0 = GETW(w0), wv1 = GETW(w1), wv2 = GETW(w2), wv3 = GETW(w3);
        a0 = fmaf(wv0, bf2f((unsigned short)(v0.x & 0xffff)), a0);
        a1 = fmaf(wv0, bf2f((unsigned short)(v0.x >> 16)), a1);
        a2 = fmaf(wv0, bf2f((unsigned short)(v0.y & 0xffff)), a2);
        a3 = fmaf(wv0, bf2f((unsigned short)(v0.y >> 16)), a3);
        a0 = fmaf(wv1, bf2f((unsigned short)(v1.x & 0xffff)), a0);
        a1 = fmaf(wv1, bf2f((unsigned short)(v1.x >> 16)), a1);
        a2 = fmaf(wv1, bf2f((unsigned short)(v1.y & 0xffff)), a2);
        a3 = fmaf(wv1, bf2f((unsigned short)(v1.y >> 16)), a3);
        a0 = fmaf(wv2, bf2f((unsigned short)(v2.x & 0xffff)), a0);
        a1 = fmaf(wv2, bf2f((unsigned short)(v2.x >> 16)), a1);
        a2 = fmaf(wv2, bf2f((unsigned short)(v2.y & 0xffff)), a2);
        a3 = fmaf(wv2, bf2f((unsigned short)(v2.y >> 16)), a3);
        a0 = fmaf(wv3, bf2f((unsigned short)(v3.x & 0xffff)), a0);
        a1 = fmaf(wv3, bf2f((unsigned short)(v3.x >> 16)), a1);
        a2 = fmaf(wv3, bf2f((unsigned short)(v3.y & 0xffff)), a2);
        a3 = fmaf(wv3, bf2f((unsigned short)(v3.y >> 16)), a3);
        sw += (wv0 + wv1) + (wv2 + wv3);
    }
    for (; p < re; p++) {
        int sn = csr_src[p];
        float4 w4 = csr_w[p];
        uint2 hv = *(const uint2*)&h1[(size_t)sn * HC + 4 * l];
        float wv = GETW(w4);
        a0 = fmaf(wv, bf2f((unsigned short)(hv.x & 0xffff)), a0);
        a1 = fmaf(wv, bf2f((unsigned short)(hv.x >> 16)), a1);
        a2 = fmaf(wv, bf2f((unsigned short)(hv.y & 0xffff)), a2);
        a3 = fmaf(wv, bf2f((unsigned short)(hv.y >> 16)), a3);
        sw += wv;
    }
    #undef GETW
    float inv = 1.f / (sw + 1e-16f);
    float4 bv = *(const float4*)&b1[4 * l];
    float o0 = fmaxf(a0 * inv + bv.x, 0.f);
    float o1 = fmaxf(a1 * inv + bv.y, 0.f);
    float o2 = fmaxf(a2 * inv + bv.z, 0.f);
    float o3 = fmaxf(a3 * inv + bv.w, 0.f);
    unsigned int* op = (unsigned int*)&out1[(size_t)node * HC + 4 * l];
    op[0] = pack2(o0, o1);
    op[1] = pack2(o2, o3);
}

// ------------- GEMM2 (N x 256)@(256 x 16) fused with attention dots, bf16 in -------------
__global__ __launch_bounds__(256) void gemm2_kernel(
    const unsigned short* __restrict__ out1, const float* __restrict__ W2,
    const float* __restrict__ att_src2, const float* __restrict__ att_dst2,
    float* __restrict__ h2, float* __restrict__ a_src2, float* __restrict__ a_dst2,
    int N)
{
    __shared__ float xs[16][260];
    __shared__ float W2s[256 * 16];
    int t = threadIdx.x;
    int rb = blockIdx.x * 16;
    {
        int r = t >> 4;
        int k0 = (t & 15) * 4;
        int gr = rb + r;
        #pragma unroll
        for (int j = 0; j < 4; j++) {
            uint2 v = make_uint2(0, 0);
            if (gr < N) v = *(const uint2*)&out1[(size_t)gr * HC + k0 + 64*j];
            xs[r][k0 + 64*j + 0] = bf2f((unsigned short)(v.x & 0xffff));
            xs[r][k0 + 64*j + 1] = bf2f((unsigned short)(v.x >> 16));
            xs[r][k0 + 64*j + 2] = bf2f((unsigned short)(v.y & 0xffff));
            xs[r][k0 + 64*j + 3] = bf2f((unsigned short)(v.y >> 16));
        }
    }
    {
        #pragma unroll
        for (int j = 0; j < 4; j++) {
            float4 v = ((const float4*)W2)[j * 256 + t];
            ((float4*)W2s)[j * 256 + t] = v;
        }
    }
    __syncthreads();
    int r = t >> 4, c = t & 15;
    float acc = 0.f;
    #pragma unroll 8
    for (int k = 0; k < 256; k++)
        acc = fmaf(xs[r][k], W2s[k * 16 + c], acc);
    int gr = rb + r;
    float ps = acc * att_src2[c];
    float pd = acc * att_dst2[c];
    #pragma unroll
    for (int off = 1; off < 16; off <<= 1) {
        ps += __shfl_xor(ps, off, 64);
        pd += __shfl_xor(pd, off, 64);
    }
    if (gr < N) {
        h2[(size_t)gr * OUT2 + c] = acc;
        if (c == 0) { a_src2[gr] = ps; a_dst2[gr] = pd; }
    }
}

// ------------- layer-2 edge weights at CSR positions -------------
__global__ __launch_bounds__(256) void w2csr_kernel(
    const int* __restrict__ csr_src, const int* __restrict__ csr_dst,
    const float* __restrict__ a_src2, const float* __restrict__ a_dst2,
    float* __restrict__ w2csr, int E)
{
    int p = blockIdx.x * blockDim.x + threadIdx.x;
    if (p >= E) return;
    float v = a_src2[csr_src[p]] + a_dst2[csr_dst[p]];
    v = v > 0.f ? v : 0.2f * v;
    w2csr[p] = __expf(v);
}

// ------------- aggregate layer2 + bias -> out -------------
// one wave per node; group g=l>>4 handles every 4th edge, c=l&15; unroll x2
__global__ __launch_bounds__(256) void agg2_kernel(
    const float* __restrict__ h2,
    const int* __restrict__ csr_src, const float* __restrict__ w2csr,
    const int* __restrict__ rowptr,
    const float* __restrict__ b2, float* __restrict__ out, int N)
{
    int wave = (int)((blockIdx.x * blockDim.x + threadIdx.x) >> 6);
    if (wave >= N) return;
    int node = __builtin_amdgcn_readfirstlane(wave);
    int l = threadIdx.x & 63;
    int g = l >> 4, c = l & 15;
    int rs = rowptr[node], re = rowptr[node + 1];
    float acc = 0.f, sw = 0.f;
    int p = rs + g;
    for (; p + 4 < re; p += 8) {
        int sn0 = csr_src[p];
        int sn1 = csr_src[p + 4];
        float w0 = w2csr[p];
        float w1 = w2csr[p + 4];
        float x0 = h2[(size_t)sn0 * OUT2 + c];
        float x1 = h2[(size_t)sn1 * OUT2 + c];
        acc = fmaf(w0, x0, acc);
        acc = fmaf(w1, x1, acc);
        sw += w0 + w1;
    }
    if (p < re) {
        int sn = csr_src[p];
        float w0 = w2csr[p];
        acc = fmaf(w0, h2[(size_t)sn * OUT2 + c], acc);
        sw += w0;
    }
    acc += __shfl_xor(acc, 16, 64);
    acc += __shfl_xor(acc, 32, 64);
    sw += __shfl_xor(sw, 16, 64);
    sw += __shfl_xor(sw, 32, 64);
    if (l < 16)
        out[(size_t)node * OUT2 + l] = acc / (sw + 1e-16f) + b2[l];
}

extern "C" void kernel_launch(void* const* d_in, const int* in_sizes, int n_in,
                              void* d_out, int out_size, void* d_ws, size_t ws_size,
                              hipStream_t stream)
{
    const float* x        = (const float*)d_in[0];
    const int*   ei       = (const int*)d_in[1];
    const float* W1       = (const float*)d_in[2];
    const float* att_src1 = (const float*)d_in[3];
    const float* att_dst1 = (const float*)d_in[4];
    const float* b1       = (const float*)d_in[5];
    const float* W2       = (const float*)d_in[6];
    const float* att_src2 = (const float*)d_in[7];
    const float* att_dst2 = (const float*)d_in[8];
    const float* b2       = (const float*)d_in[9];
    float* out = (float*)d_out;

    const int N = in_sizes[0] / FIN;
    const int E = in_sizes[1] / 2;
    const int* srcv = ei;
    const int* dstv = ei + E;

    char* base = (char*)d_ws;
    #define ALLOC(ptr, type, nelem) \
        type* ptr = (type*)base; base += (((size_t)(nelem) * sizeof(type) + 255) & ~(size_t)255);
    ALLOC(h1,      unsigned short, (size_t)N * HC)
    ALLOC(out1,    unsigned short, (size_t)N * HC)
    ALLOC(csr_w,   float4,         (size_t)E)
    ALLOC(h2,      float,          (size_t)N * OUT2)
    ALLOC(a_src1v, float,          (size_t)N * 4)
    ALLOC(a_dst1v, float,          (size_t)N * 4)
    ALLOC(a_src2v, float,          (size_t)N)
    ALLOC(a_dst2v, float,          (size_t)N)
    ALLOC(counts,  int,            (size_t)2 * N)      // counts + cursor adjacent
    ALLOC(csr_src, int,            (size_t)E)
    ALLOC(csr_dst, int,            (size_t)E)
    ALLOC(w2csr,   float,          (size_t)E)
    ALLOC(rowptr,  int,            (size_t)N + 1)
    ALLOC(bsum,    int,            1024)
    #undef ALLOC
    int* cursor = counts + N;

    const int nb = (N + 1023) / 1024;

    hipMemsetAsync(counts, 0, sizeof(int) * 2 * (size_t)N, stream);

    gemm1_kernel<<<(N + 63) / 64, 256, 0, stream>>>(x, W1, h1, N);
    attdots1_kernel<<<(N + 3) / 4, 256, 0, stream>>>(h1, att_src1, att_dst1, a_src1v, a_dst1v, N);
    count_kernel<<<(E + 255) / 256, 256, 0, stream>>>(dstv, counts, E);
    scan1_kernel<<<nb, 1024, 0, stream>>>(counts, rowptr, bsum, N);
    scan2_kernel<<<1, 1024, 0, stream>>>(bsum, rowptr, nb, N, E);
    scan3_kernel<<<nb, 1024, 0, stream>>>(rowptr, bsum, N);
    scatter_kernel<<<(E + 255) / 256, 256, 0, stream>>>(srcv, dstv, rowptr, cursor,
                                                        a_src1v, a_dst1v,
                                                        csr_src, csr_dst, csr_w, E);
    agg1_kernel<<<(N + 3) / 4, 256, 0, stream>>>(h1, csr_src, csr_w, rowptr, b1, out1, N);
    gemm2_kernel<<<(N + 15) / 16, 256, 0, stream>>>(out1, W2, att_src2, att_dst2, h2, a_src2v, a_dst2v, N);
    w2csr_kernel<<<(E + 255) / 256, 256, 0, stream>>>(csr_src, csr_dst, a_src2v, a_dst2v, w2csr, E);
    agg2_kernel<<<(N + 3) / 4, 256, 0, stream>>>(h2, csr_src, w2csr, rowptr, b2, out, N);
}

// Round 5
// 261.285 us; speedup vs baseline: 1.9294x; 1.0249x over previous
//
#include <hip/hip_runtime.h>
#include <hip/hip_bf16.h>

#define FIN 128
#define HC 256
#define H1 4
#define C1 64
#define OUT2 16

__device__ inline float bf2f(unsigned short u) {
    union { unsigned int i; float f; } v; v.i = ((unsigned int)u) << 16; return v.f;
}
__device__ inline unsigned short f2bf(float f) {
    union { float f; unsigned int i; } v; v.f = f;
    unsigned int i = v.i;
    return (unsigned short)((i + 0x7FFFu + ((i >> 16) & 1u)) >> 16);
}
__device__ inline unsigned int pack2(float a, float b) {
    return (unsigned int)f2bf(a) | ((unsigned int)f2bf(b) << 16);
}

// ---------------- GEMM1: h1 = x @ W1  (N x 128) @ (128 x 256), bf16 out ----------------
__global__ __launch_bounds__(256) void gemm1_kernel(
    const float* __restrict__ x, const float* __restrict__ W1,
    unsigned short* __restrict__ h1, int N)
{
    __shared__ float As[32][68];   // [k][row], padded
    __shared__ float Bs[32][260];  // [k][col], padded
    const int t = threadIdx.x;
    const int rb = blockIdx.x * 64;
    const int rg = t >> 5;          // 0..7 row-group
    const int cg = t & 31;          // col group
    const int r0 = rg * 8;

    float2 acc[8][4];
    #pragma unroll
    for (int i = 0; i < 8; i++)
        #pragma unroll
        for (int j = 0; j < 4; j++) acc[i][j] = make_float2(0.f, 0.f);

    for (int kb = 0; kb < FIN; kb += 32) {
        {
            int row = t >> 2;
            int k8 = (t & 3) * 8;
            int gr = rb + row;
            float4 v0 = make_float4(0,0,0,0), v1 = make_float4(0,0,0,0);
            if (gr < N) {
                v0 = *(const float4*)&x[(size_t)gr * FIN + kb + k8];
                v1 = *(const float4*)&x[(size_t)gr * FIN + kb + k8 + 4];
            }
            As[k8+0][row] = v0.x; As[k8+1][row] = v0.y; As[k8+2][row] = v0.z; As[k8+3][row] = v0.w;
            As[k8+4][row] = v1.x; As[k8+5][row] = v1.y; As[k8+6][row] = v1.z; As[k8+7][row] = v1.w;
        }
        {
            int k = t >> 3;
            int c4 = (t & 7) * 4;
            #pragma unroll
            for (int j = 0; j < 8; j++) {
                float4 v = *(const float4*)&W1[(size_t)(kb + k) * HC + c4 + 32*j];
                *(float4*)&Bs[k][c4 + 32*j] = v;
            }
        }
        __syncthreads();
        #pragma unroll 4
        for (int k = 0; k < 32; k++) {
            float4 aA = *(const float4*)&As[k][r0];
            float4 aB = *(const float4*)&As[k][r0 + 4];
            float2 b[4];
            #pragma unroll
            for (int j = 0; j < 4; j++) b[j] = *(const float2*)&Bs[k][2*cg + 64*j];
            float av[8] = {aA.x, aA.y, aA.z, aA.w, aB.x, aB.y, aB.z, aB.w};
            #pragma unroll
            for (int i = 0; i < 8; i++) {
                #pragma unroll
                for (int j = 0; j < 4; j++) {
                    acc[i][j].x = fmaf(av[i], b[j].x, acc[i][j].x);
                    acc[i][j].y = fmaf(av[i], b[j].y, acc[i][j].y);
                }
            }
        }
        __syncthreads();
    }
    #pragma unroll
    for (int i = 0; i < 8; i++) {
        int gr = rb + r0 + i;
        if (gr < N) {
            unsigned int* hp = (unsigned int*)&h1[(size_t)gr * HC];
            #pragma unroll
            for (int j = 0; j < 4; j++)
                hp[cg + 32*j] = pack2(acc[i][j].x, acc[i][j].y);
        }
    }
}

// ------------- attention dots layer1 (bf16 h1) -------------
__global__ __launch_bounds__(256) void attdots1_kernel(
    const unsigned short* __restrict__ h1, const float* __restrict__ att_src,
    const float* __restrict__ att_dst, float* __restrict__ a_src,
    float* __restrict__ a_dst, int N)
{
    int wave = (int)((blockIdx.x * blockDim.x + threadIdx.x) >> 6);
    int l = threadIdx.x & 63;
    if (wave >= N) return;
    int h = l >> 4;
    int ci = 4 * (l & 15);
    uint2 hv = *(const uint2*)&h1[(size_t)wave * HC + 4*l];
    float f0 = bf2f((unsigned short)(hv.x & 0xffff));
    float f1 = bf2f((unsigned short)(hv.x >> 16));
    float f2 = bf2f((unsigned short)(hv.y & 0xffff));
    float f3 = bf2f((unsigned short)(hv.y >> 16));
    float4 asv = *(const float4*)&att_src[h * C1 + ci];
    float4 adv = *(const float4*)&att_dst[h * C1 + ci];
    float ps = f0*asv.x + f1*asv.y + f2*asv.z + f3*asv.w;
    float pd = f0*adv.x + f1*adv.y + f2*adv.z + f3*adv.w;
    #pragma unroll
    for (int off = 1; off < 16; off <<= 1) {
        ps += __shfl_xor(ps, off, 64);
        pd += __shfl_xor(pd, off, 64);
    }
    if ((l & 15) == 0) {
        a_src[wave * 4 + h] = ps;
        a_dst[wave * 4 + h] = pd;
    }
}

// ---------------- CSR build ----------------
__global__ __launch_bounds__(256) void count_kernel(
    const int* __restrict__ dst, int* __restrict__ counts, int E)
{
    int e = blockIdx.x * blockDim.x + threadIdx.x;
    if (e < E) atomicAdd(&counts[dst[e]], 1);
}

__global__ __launch_bounds__(1024) void scan1_kernel(
    const int* __restrict__ counts, int* __restrict__ rowptr,
    int* __restrict__ bsum, int n)
{
    __shared__ int sm[1024];
    int tid = threadIdx.x;
    int i = blockIdx.x * 1024 + tid;
    int v = (i < n) ? counts[i] : 0;
    sm[tid] = v;
    __syncthreads();
    for (int off = 1; off < 1024; off <<= 1) {
        int tv = (tid >= off) ? sm[tid - off] : 0;
        __syncthreads();
        sm[tid] += tv;
        __syncthreads();
    }
    if (i < n) rowptr[i] = sm[tid] - v;     // block-local exclusive
    if (tid == 1023) bsum[blockIdx.x] = sm[1023];
}

__global__ __launch_bounds__(1024) void scan2_kernel(
    int* __restrict__ bsum, int* __restrict__ rowptr, int nb, int N, int E)
{
    __shared__ int sm[1024];
    int tid = threadIdx.x;
    int v = (tid < nb) ? bsum[tid] : 0;
    sm[tid] = v;
    __syncthreads();
    for (int off = 1; off < 1024; off <<= 1) {
        int tv = (tid >= off) ? sm[tid - off] : 0;
        __syncthreads();
        sm[tid] += tv;
        __syncthreads();
    }
    if (tid < nb) bsum[tid] = sm[tid] - v;  // exclusive block offsets
    if (tid == 0) rowptr[N] = E;
}

__global__ __launch_bounds__(1024) void scan3_kernel(
    int* __restrict__ rowptr, const int* __restrict__ bsum, int n)
{
    int i = blockIdx.x * 1024 + threadIdx.x;
    if (i < n) rowptr[i] += bsum[blockIdx.x];
}

// scatter: single packed 16B record per edge: {src, dst, w01(bf16x2), w23(bf16x2)}
__global__ __launch_bounds__(256) void scatter_kernel(
    const int* __restrict__ src, const int* __restrict__ dst,
    const int* __restrict__ rowptr, int* __restrict__ cursor,
    const float* __restrict__ a_src, const float* __restrict__ a_dst,
    uint4* __restrict__ csr_rec, int E)
{
    int e = blockIdx.x * blockDim.x + threadIdx.x;
    if (e >= E) return;
    int s = src[e], d = dst[e];
    int pos = rowptr[d] + atomicAdd(&cursor[d], 1);
    float4 av = *(const float4*)&a_src[(size_t)s * 4];
    float4 bv = *(const float4*)&a_dst[(size_t)d * 4];
    float w0, w1, w2, w3, v;
    v = av.x + bv.x; v = v > 0.f ? v : 0.2f * v; w0 = __expf(v);
    v = av.y + bv.y; v = v > 0.f ? v : 0.2f * v; w1 = __expf(v);
    v = av.z + bv.z; v = v > 0.f ? v : 0.2f * v; w2 = __expf(v);
    v = av.w + bv.w; v = v > 0.f ? v : 0.2f * v; w3 = __expf(v);
    uint4 rec;
    rec.x = (unsigned int)s;
    rec.y = (unsigned int)d;
    rec.z = pack2(w0, w1);
    rec.w = pack2(w2, w3);
    csr_rec[pos] = rec;
}

// ------------- aggregate layer1 + bias + relu, bf16 out -------------
// one wave per node; lane l owns out elements 4l..4l+3 (head h=l>>4); unroll x8
__global__ __launch_bounds__(256) void agg1_kernel(
    const unsigned short* __restrict__ h1,
    const uint4* __restrict__ csr_rec, const int* __restrict__ rowptr,
    const float* __restrict__ b1, unsigned short* __restrict__ out1, int N)
{
    int wave = (int)((blockIdx.x * blockDim.x + threadIdx.x) >> 6);
    if (wave >= N) return;
    int node = __builtin_amdgcn_readfirstlane(wave);
    int l = threadIdx.x & 63;
    int h = l >> 4;
    int rs = rowptr[node], re = rowptr[node + 1];
    float a0 = 0.f, a1 = 0.f, a2 = 0.f, a3 = 0.f, sw = 0.f;
    int p = rs;
    for (; p + 8 <= re; p += 8) {
        uint4 r[8];
        #pragma unroll
        for (int j = 0; j < 8; j++) r[j] = csr_rec[p + j];
        uint2 hv[8];
        #pragma unroll
        for (int j = 0; j < 8; j++)
            hv[j] = *(const uint2*)&h1[(size_t)(int)r[j].x * HC + 4 * l];
        #pragma unroll
        for (int j = 0; j < 8; j++) {
            unsigned int wsel = (h & 2) ? r[j].w : r[j].z;
            float wv = bf2f((unsigned short)((h & 1) ? (wsel >> 16) : (wsel & 0xffff)));
            a0 = fmaf(wv, bf2f((unsigned short)(hv[j].x & 0xffff)), a0);
            a1 = fmaf(wv, bf2f((unsigned short)(hv[j].x >> 16)), a1);
            a2 = fmaf(wv, bf2f((unsigned short)(hv[j].y & 0xffff)), a2);
            a3 = fmaf(wv, bf2f((unsigned short)(hv[j].y >> 16)), a3);
            sw += wv;
        }
    }
    for (; p < re; p++) {
        uint4 r = csr_rec[p];
        uint2 hv = *(const uint2*)&h1[(size_t)(int)r.x * HC + 4 * l];
        unsigned int wsel = (h & 2) ? r.w : r.z;
        float wv = bf2f((unsigned short)((h & 1) ? (wsel >> 16) : (wsel & 0xffff)));
        a0 = fmaf(wv, bf2f((unsigned short)(hv.x & 0xffff)), a0);
        a1 = fmaf(wv, bf2f((unsigned short)(hv.x >> 16)), a1);
        a2 = fmaf(wv, bf2f((unsigned short)(hv.y & 0xffff)), a2);
        a3 = fmaf(wv, bf2f((unsigned short)(hv.y >> 16)), a3);
        sw += wv;
    }
    float inv = 1.f / (sw + 1e-16f);
    float4 bv = *(const float4*)&b1[4 * l];
    float o0 = fmaxf(a0 * inv + bv.x, 0.f);
    float o1 = fmaxf(a1 * inv + bv.y, 0.f);
    float o2 = fmaxf(a2 * inv + bv.z, 0.f);
    float o3 = fmaxf(a3 * inv + bv.w, 0.f);
    unsigned int* op = (unsigned int*)&out1[(size_t)node * HC + 4 * l];
    op[0] = pack2(o0, o1);
    op[1] = pack2(o2, o3);
}

// ------------- GEMM2 (N x 256)@(256 x 16) fused with attention dots, bf16 in -------------
__global__ __launch_bounds__(256) void gemm2_kernel(
    const unsigned short* __restrict__ out1, const float* __restrict__ W2,
    const float* __restrict__ att_src2, const float* __restrict__ att_dst2,
    float* __restrict__ h2, float* __restrict__ a_src2, float* __restrict__ a_dst2,
    int N)
{
    __shared__ float xs[16][260];
    __shared__ float W2s[256 * 16];
    int t = threadIdx.x;
    int rb = blockIdx.x * 16;
    {
        int r = t >> 4;
        int k0 = (t & 15) * 4;
        int gr = rb + r;
        #pragma unroll
        for (int j = 0; j < 4; j++) {
            uint2 v = make_uint2(0, 0);
            if (gr < N) v = *(const uint2*)&out1[(size_t)gr * HC + k0 + 64*j];
            xs[r][k0 + 64*j + 0] = bf2f((unsigned short)(v.x & 0xffff));
            xs[r][k0 + 64*j + 1] = bf2f((unsigned short)(v.x >> 16));
            xs[r][k0 + 64*j + 2] = bf2f((unsigned short)(v.y & 0xffff));
            xs[r][k0 + 64*j + 3] = bf2f((unsigned short)(v.y >> 16));
        }
    }
    {
        #pragma unroll
        for (int j = 0; j < 4; j++) {
            float4 v = ((const float4*)W2)[j * 256 + t];
            ((float4*)W2s)[j * 256 + t] = v;
        }
    }
    __syncthreads();
    int r = t >> 4, c = t & 15;
    float acc = 0.f;
    #pragma unroll 8
    for (int k = 0; k < 256; k++)
        acc = fmaf(xs[r][k], W2s[k * 16 + c], acc);
    int gr = rb + r;
    float ps = acc * att_src2[c];
    float pd = acc * att_dst2[c];
    #pragma unroll
    for (int off = 1; off < 16; off <<= 1) {
        ps += __shfl_xor(ps, off, 64);
        pd += __shfl_xor(pd, off, 64);
    }
    if (gr < N) {
        h2[(size_t)gr * OUT2 + c] = acc;
        if (c == 0) { a_src2[gr] = ps; a_dst2[gr] = pd; }
    }
}

// ------------- layer-2 edge weights at CSR positions (coalesced rec read) -------------
__global__ __launch_bounds__(256) void w2csr_kernel(
    const uint4* __restrict__ csr_rec,
    const float* __restrict__ a_src2, const float* __restrict__ a_dst2,
    float* __restrict__ w2csr, int E)
{
    int p = blockIdx.x * blockDim.x + threadIdx.x;
    if (p >= E) return;
    uint4 r = csr_rec[p];
    float v = a_src2[(int)r.x] + a_dst2[(int)r.y];
    v = v > 0.f ? v : 0.2f * v;
    w2csr[p] = __expf(v);
}

// ------------- aggregate layer2 + bias -> out -------------
// one wave per node; group g=l>>4 handles every 4th edge, c=l&15; unroll x2
__global__ __launch_bounds__(256) void agg2_kernel(
    const float* __restrict__ h2,
    const int* __restrict__ csr_rec_i, const float* __restrict__ w2csr,
    const int* __restrict__ rowptr,
    const float* __restrict__ b2, float* __restrict__ out, int N)
{
    int wave = (int)((blockIdx.x * blockDim.x + threadIdx.x) >> 6);
    if (wave >= N) return;
    int node = __builtin_amdgcn_readfirstlane(wave);
    int l = threadIdx.x & 63;
    int g = l >> 4, c = l & 15;
    int rs = rowptr[node], re = rowptr[node + 1];
    float acc = 0.f, sw = 0.f;
    int p = rs + g;
    for (; p + 4 < re; p += 8) {
        int sn0 = csr_rec_i[(size_t)p * 4];
        int sn1 = csr_rec_i[(size_t)(p + 4) * 4];
        float w0 = w2csr[p];
        float w1 = w2csr[p + 4];
        float x0 = h2[(size_t)sn0 * OUT2 + c];
        float x1 = h2[(size_t)sn1 * OUT2 + c];
        acc = fmaf(w0, x0, acc);
        acc = fmaf(w1, x1, acc);
        sw += w0 + w1;
    }
    if (p < re) {
        int sn = csr_rec_i[(size_t)p * 4];
        float w0 = w2csr[p];
        acc = fmaf(w0, h2[(size_t)sn * OUT2 + c], acc);
        sw += w0;
    }
    acc += __shfl_xor(acc, 16, 64);
    acc += __shfl_xor(acc, 32, 64);
    sw += __shfl_xor(sw, 16, 64);
    sw += __shfl_xor(sw, 32, 64);
    if (l < 16)
        out[(size_t)node * OUT2 + l] = acc / (sw + 1e-16f) + b2[l];
}

extern "C" void kernel_launch(void* const* d_in, const int* in_sizes, int n_in,
                              void* d_out, int out_size, void* d_ws, size_t ws_size,
                              hipStream_t stream)
{
    const float* x        = (const float*)d_in[0];
    const int*   ei       = (const int*)d_in[1];
    const float* W1       = (const float*)d_in[2];
    const float* att_src1 = (const float*)d_in[3];
    const float* att_dst1 = (const float*)d_in[4];
    const float* b1       = (const float*)d_in[5];
    const float* W2       = (const float*)d_in[6];
    const float* att_src2 = (const float*)d_in[7];
    const float* att_dst2 = (const float*)d_in[8];
    const float* b2       = (const float*)d_in[9];
    float* out = (float*)d_out;

    const int N = in_sizes[0] / FIN;
    const int E = in_sizes[1] / 2;
    const int* srcv = ei;
    const int* dstv = ei + E;

    char* base = (char*)d_ws;
    #define ALLOC(ptr, type, nelem) \
        type* ptr = (type*)base; base += (((size_t)(nelem) * sizeof(type) + 255) & ~(size_t)255);
    ALLOC(h1,      unsigned short, (size_t)N * HC)
    ALLOC(out1,    unsigned short, (size_t)N * HC)
    ALLOC(csr_rec, uint4,          (size_t)E)
    ALLOC(h2,      float,          (size_t)N * OUT2)
    ALLOC(a_src1v, float,          (size_t)N * 4)
    ALLOC(a_dst1v, float,          (size_t)N * 4)
    ALLOC(a_src2v, float,          (size_t)N)
    ALLOC(a_dst2v, float,          (size_t)N)
    ALLOC(counts,  int,            (size_t)2 * N)      // counts + cursor adjacent
    ALLOC(w2csr,   float,          (size_t)E)
    ALLOC(rowptr,  int,            (size_t)N + 1)
    ALLOC(bsum,    int,            1024)
    #undef ALLOC
    int* cursor = counts + N;

    const int nb = (N + 1023) / 1024;

    (void)hipMemsetAsync(counts, 0, sizeof(int) * 2 * (size_t)N, stream);

    gemm1_kernel<<<(N + 63) / 64, 256, 0, stream>>>(x, W1, h1, N);
    attdots1_kernel<<<(N + 3) / 4, 256, 0, stream>>>(h1, att_src1, att_dst1, a_src1v, a_dst1v, N);
    count_kernel<<<(E + 255) / 256, 256, 0, stream>>>(dstv, counts, E);
    scan1_kernel<<<nb, 1024, 0, stream>>>(counts, rowptr, bsum, N);
    scan2_kernel<<<1, 1024, 0, stream>>>(bsum, rowptr, nb, N, E);
    scan3_kernel<<<nb, 1024, 0, stream>>>(rowptr, bsum, N);
    scatter_kernel<<<(E + 255) / 256, 256, 0, stream>>>(srcv, dstv, rowptr, cursor,
                                                        a_src1v, a_dst1v, csr_rec, E);
    agg1_kernel<<<(N + 3) / 4, 256, 0, stream>>>(h1, csr_rec, rowptr, b1, out1, N);
    gemm2_kernel<<<(N + 15) / 16, 256, 0, stream>>>(out1, W2, att_src2, att_dst2, h2, a_src2v, a_dst2v, N);
    w2csr_kernel<<<(E + 255) / 256, 256, 0, stream>>>(csr_rec, a_src2v, a_dst2v, w2csr, E);
    agg2_kernel<<<(N + 3) / 4, 256, 0, stream>>>(h2, (const int*)csr_rec, w2csr, rowptr, b2, out, N);
}

// Round 7
// 253.422 us; speedup vs baseline: 1.9892x; 1.0310x over previous
//
#include <hip/hip_runtime.h>
#include <hip/hip_bf16.h>

#define FIN 128
#define HC 256
#define H1 4
#define C1 64
#define OUT2 16

typedef __attribute__((ext_vector_type(8))) short bf16x8;
typedef __attribute__((ext_vector_type(4))) float f32x4;

__device__ inline float bf2f(unsigned short u) {
    union { unsigned int i; float f; } v; v.i = ((unsigned int)u) << 16; return v.f;
}
__device__ inline unsigned short f2bf(float f) {
    union { float f; unsigned int i; } v; v.f = f;
    unsigned int i = v.i;
    return (unsigned short)((i + 0x7FFFu + ((i >> 16) & 1u)) >> 16);
}
__device__ inline unsigned int pack2(float a, float b) {
    return (unsigned int)f2bf(a) | ((unsigned int)f2bf(b) << 16);
}

// ------------- W1 transpose to bf16: W1t[col][k] = bf16(W1[k][col]) -------------
__global__ __launch_bounds__(256) void w1t_kernel(
    const float* __restrict__ W1, unsigned short* __restrict__ W1t)
{
    int t = blockIdx.x * 256 + threadIdx.x;   // 32768 total
    if (t >= HC * FIN) return;
    int c = t >> 7, k = t & 127;
    W1t[t] = f2bf(W1[k * HC + c]);
}

// ------------- GEMM1 via MFMA bf16 (no fused epilogue) -------------
// block = 256 thr = 4 waves; wave handles 16 rows x 256 cols; K=128 in 4 steps of 32.
// A-frag: row = lane&15, k = 8*(lane>>4)+e (from x, cvt in flight)
// B-frag: col = lane&15, k = 8*(lane>>4)+e (from W1t, contiguous 16B)
// D: col = lane&15, row = 4*(lane>>4)+reg
__global__ __launch_bounds__(256) void gemm1_mfma_kernel(
    const float* __restrict__ x, const unsigned short* __restrict__ W1t,
    unsigned short* __restrict__ h1, int N)
{
    const int t  = threadIdx.x;
    const int wv = t >> 6;
    const int l  = t & 63;
    const int c0 = l & 15;
    const int h  = l >> 4;
    const int R0 = blockIdx.x * 64 + wv * 16;

    f32x4 acc[16];
    #pragma unroll
    for (int j = 0; j < 16; j++) acc[j] = (f32x4){0.f, 0.f, 0.f, 0.f};

    int arow = R0 + c0;
    if (arow > N - 1) arow = N - 1;        // clamp loads; stores are guarded
    const float* xrow = x + (size_t)arow * FIN;

    for (int kb = 0; kb < FIN; kb += 32) {
        float4 f0 = *(const float4*)&xrow[kb + 8 * h];
        float4 f1 = *(const float4*)&xrow[kb + 8 * h + 4];
        union { bf16x8 v; unsigned int u[4]; } af;
        af.u[0] = pack2(f0.x, f0.y);
        af.u[1] = pack2(f0.z, f0.w);
        af.u[2] = pack2(f1.x, f1.y);
        af.u[3] = pack2(f1.z, f1.w);
        #pragma unroll
        for (int j = 0; j < 16; j++) {
            int col = 16 * j + c0;
            union { bf16x8 v; uint4 u; } bf;
            bf.u = *(const uint4*)&W1t[(size_t)col * FIN + kb + 8 * h];
            acc[j] = __builtin_amdgcn_mfma_f32_16x16x32_bf16(af.v, bf.v, acc[j], 0, 0, 0);
        }
    }

    // ---- h1 store (bf16)
    #pragma unroll
    for (int r = 0; r < 4; r++) {
        int row = R0 + 4 * h + r;
        if (row < N) {
            unsigned short* hp = &h1[(size_t)row * HC + c0];
            #pragma unroll
            for (int j = 0; j < 16; j++)
                hp[16 * j] = f2bf(acc[j][r]);
        }
    }
}

// ------------- attention dots layer1 (bf16 h1) -------------
__global__ __launch_bounds__(256) void attdots1_kernel(
    const unsigned short* __restrict__ h1, const float* __restrict__ att_src,
    const float* __restrict__ att_dst, float* __restrict__ a_src,
    float* __restrict__ a_dst, int N)
{
    int wave = (int)((blockIdx.x * blockDim.x + threadIdx.x) >> 6);
    int l = threadIdx.x & 63;
    if (wave >= N) return;
    int h = l >> 4;
    int ci = 4 * (l & 15);
    uint2 hv = *(const uint2*)&h1[(size_t)wave * HC + 4*l];
    float f0 = bf2f((unsigned short)(hv.x & 0xffff));
    float f1 = bf2f((unsigned short)(hv.x >> 16));
    float f2 = bf2f((unsigned short)(hv.y & 0xffff));
    float f3 = bf2f((unsigned short)(hv.y >> 16));
    float4 asv = *(const float4*)&att_src[h * C1 + ci];
    float4 adv = *(const float4*)&att_dst[h * C1 + ci];
    float ps = f0*asv.x + f1*asv.y + f2*asv.z + f3*asv.w;
    float pd = f0*adv.x + f1*adv.y + f2*adv.z + f3*adv.w;
    #pragma unroll
    for (int off = 1; off < 16; off <<= 1) {
        ps += __shfl_xor(ps, off, 64);
        pd += __shfl_xor(pd, off, 64);
    }
    if ((l & 15) == 0) {
        a_src[wave * 4 + h] = ps;
        a_dst[wave * 4 + h] = pd;
    }
}

// ---------------- CSR build ----------------
__global__ __launch_bounds__(256) void count_kernel(
    const int* __restrict__ dst, int* __restrict__ counts, int E)
{
    int e = blockIdx.x * blockDim.x + threadIdx.x;
    if (e < E) atomicAdd(&counts[dst[e]], 1);
}

__global__ __launch_bounds__(1024) void scan1_kernel(
    const int* __restrict__ counts, int* __restrict__ rowptr,
    int* __restrict__ bsum, int n)
{
    __shared__ int sm[1024];
    int tid = threadIdx.x;
    int i = blockIdx.x * 1024 + tid;
    int v = (i < n) ? counts[i] : 0;
    sm[tid] = v;
    __syncthreads();
    for (int off = 1; off < 1024; off <<= 1) {
        int tv = (tid >= off) ? sm[tid - off] : 0;
        __syncthreads();
        sm[tid] += tv;
        __syncthreads();
    }
    if (i < n) rowptr[i] = sm[tid] - v;     // block-local exclusive
    if (tid == 1023) bsum[blockIdx.x] = sm[1023];
}

__global__ __launch_bounds__(1024) void scan2_kernel(
    int* __restrict__ bsum, int* __restrict__ rowptr, int nb, int N, int E)
{
    __shared__ int sm[1024];
    int tid = threadIdx.x;
    int v = (tid < nb) ? bsum[tid] : 0;
    sm[tid] = v;
    __syncthreads();
    for (int off = 1; off < 1024; off <<= 1) {
        int tv = (tid >= off) ? sm[tid - off] : 0;
        __syncthreads();
        sm[tid] += tv;
        __syncthreads();
    }
    if (tid < nb) bsum[tid] = sm[tid] - v;  // exclusive block offsets
    if (tid == 0) rowptr[N] = E;
}

__global__ __launch_bounds__(1024) void scan3_kernel(
    int* __restrict__ rowptr, const int* __restrict__ bsum, int n)
{
    int i = blockIdx.x * 1024 + threadIdx.x;
    if (i < n) rowptr[i] += bsum[blockIdx.x];
}

// scatter: single packed 16B record per edge: {src, dst, w01(bf16x2), w23(bf16x2)}
__global__ __launch_bounds__(256) void scatter_kernel(
    const int* __restrict__ src, const int* __restrict__ dst,
    const int* __restrict__ rowptr, int* __restrict__ cursor,
    const float* __restrict__ a_src, const float* __restrict__ a_dst,
    uint4* __restrict__ csr_rec, int E)
{
    int e = blockIdx.x * blockDim.x + threadIdx.x;
    if (e >= E) return;
    int s = src[e], d = dst[e];
    int pos = rowptr[d] + atomicAdd(&cursor[d], 1);
    float4 av = *(const float4*)&a_src[(size_t)s * 4];
    float4 bv = *(const float4*)&a_dst[(size_t)d * 4];
    float w0, w1, w2, w3, v;
    v = av.x + bv.x; v = v > 0.f ? v : 0.2f * v; w0 = __expf(v);
    v = av.y + bv.y; v = v > 0.f ? v : 0.2f * v; w1 = __expf(v);
    v = av.z + bv.z; v = v > 0.f ? v : 0.2f * v; w2 = __expf(v);
    v = av.w + bv.w; v = v > 0.f ? v : 0.2f * v; w3 = __expf(v);
    uint4 rec;
    rec.x = (unsigned int)s;
    rec.y = (unsigned int)d;
    rec.z = pack2(w0, w1);
    rec.w = pack2(w2, w3);
    csr_rec[pos] = rec;
}

// ------------- aggregate layer1 + bias + relu, bf16 out -------------
__global__ __launch_bounds__(256) void agg1_kernel(
    const unsigned short* __restrict__ h1,
    const uint4* __restrict__ csr_rec, const int* __restrict__ rowptr,
    const float* __restrict__ b1, unsigned short* __restrict__ out1, int N)
{
    int wave = (int)((blockIdx.x * blockDim.x + threadIdx.x) >> 6);
    if (wave >= N) return;
    int node = __builtin_amdgcn_readfirstlane(wave);
    int l = threadIdx.x & 63;
    int h = l >> 4;
    int rs = rowptr[node], re = rowptr[node + 1];
    float a0 = 0.f, a1 = 0.f, a2 = 0.f, a3 = 0.f, sw = 0.f;
    int p = rs;
    for (; p + 8 <= re; p += 8) {
        uint4 r[8];
        #pragma unroll
        for (int j = 0; j < 8; j++) r[j] = csr_rec[p + j];
        uint2 hv[8];
        #pragma unroll
        for (int j = 0; j < 8; j++)
            hv[j] = *(const uint2*)&h1[(size_t)(int)r[j].x * HC + 4 * l];
        #pragma unroll
        for (int j = 0; j < 8; j++) {
            unsigned int wsel = (h & 2) ? r[j].w : r[j].z;
            float wv = bf2f((unsigned short)((h & 1) ? (wsel >> 16) : (wsel & 0xffff)));
            a0 = fmaf(wv, bf2f((unsigned short)(hv[j].x & 0xffff)), a0);
            a1 = fmaf(wv, bf2f((unsigned short)(hv[j].x >> 16)), a1);
            a2 = fmaf(wv, bf2f((unsigned short)(hv[j].y & 0xffff)), a2);
            a3 = fmaf(wv, bf2f((unsigned short)(hv[j].y >> 16)), a3);
            sw += wv;
        }
    }
    for (; p < re; p++) {
        uint4 r = csr_rec[p];
        uint2 hv = *(const uint2*)&h1[(size_t)(int)r.x * HC + 4 * l];
        unsigned int wsel = (h & 2) ? r.w : r.z;
        float wv = bf2f((unsigned short)((h & 1) ? (wsel >> 16) : (wsel & 0xffff)));
        a0 = fmaf(wv, bf2f((unsigned short)(hv.x & 0xffff)), a0);
        a1 = fmaf(wv, bf2f((unsigned short)(hv.x >> 16)), a1);
        a2 = fmaf(wv, bf2f((unsigned short)(hv.y & 0xffff)), a2);
        a3 = fmaf(wv, bf2f((unsigned short)(hv.y >> 16)), a3);
        sw += wv;
    }
    float inv = 1.f / (sw + 1e-16f);
    float4 bv = *(const float4*)&b1[4 * l];
    float o0 = fmaxf(a0 * inv + bv.x, 0.f);
    float o1 = fmaxf(a1 * inv + bv.y, 0.f);
    float o2 = fmaxf(a2 * inv + bv.z, 0.f);
    float o3 = fmaxf(a3 * inv + bv.w, 0.f);
    unsigned int* op = (unsigned int*)&out1[(size_t)node * HC + 4 * l];
    op[0] = pack2(o0, o1);
    op[1] = pack2(o2, o3);
}

// ------------- GEMM2 (N x 256)@(256 x 16) fused with attention dots, bf16 in -------------
__global__ __launch_bounds__(256) void gemm2_kernel(
    const unsigned short* __restrict__ out1, const float* __restrict__ W2,
    const float* __restrict__ att_src2, const float* __restrict__ att_dst2,
    float* __restrict__ h2, float* __restrict__ a_src2, float* __restrict__ a_dst2,
    int N)
{
    __shared__ float xs[16][260];
    __shared__ float W2s[256 * 16];
    int t = threadIdx.x;
    int rb = blockIdx.x * 16;
    {
        int r = t >> 4;
        int k0 = (t & 15) * 4;
        int gr = rb + r;
        #pragma unroll
        for (int j = 0; j < 4; j++) {
            uint2 v = make_uint2(0, 0);
            if (gr < N) v = *(const uint2*)&out1[(size_t)gr * HC + k0 + 64*j];
            xs[r][k0 + 64*j + 0] = bf2f((unsigned short)(v.x & 0xffff));
            xs[r][k0 + 64*j + 1] = bf2f((unsigned short)(v.x >> 16));
            xs[r][k0 + 64*j + 2] = bf2f((unsigned short)(v.y & 0xffff));
            xs[r][k0 + 64*j + 3] = bf2f((unsigned short)(v.y >> 16));
        }
    }
    {
        #pragma unroll
        for (int j = 0; j < 4; j++) {
            float4 v = ((const float4*)W2)[j * 256 + t];
            ((float4*)W2s)[j * 256 + t] = v;
        }
    }
    __syncthreads();
    int r = t >> 4, c = t & 15;
    float acc = 0.f;
    #pragma unroll 8
    for (int k = 0; k < 256; k++)
        acc = fmaf(xs[r][k], W2s[k * 16 + c], acc);
    int gr = rb + r;
    float ps = acc * att_src2[c];
    float pd = acc * att_dst2[c];
    #pragma unroll
    for (int off = 1; off < 16; off <<= 1) {
        ps += __shfl_xor(ps, off, 64);
        pd += __shfl_xor(pd, off, 64);
    }
    if (gr < N) {
        h2[(size_t)gr * OUT2 + c] = acc;
        if (c == 0) { a_src2[gr] = ps; a_dst2[gr] = pd; }
    }
}

// ------------- layer-2 edge weights at CSR positions (coalesced rec read) -------------
__global__ __launch_bounds__(256) void w2csr_kernel(
    const uint4* __restrict__ csr_rec,
    const float* __restrict__ a_src2, const float* __restrict__ a_dst2,
    float* __restrict__ w2csr, int E)
{
    int p = blockIdx.x * blockDim.x + threadIdx.x;
    if (p >= E) return;
    uint4 r = csr_rec[p];
    float v = a_src2[(int)r.x] + a_dst2[(int)r.y];
    v = v > 0.f ? v : 0.2f * v;
    w2csr[p] = __expf(v);
}

// ------------- aggregate layer2 + bias -> out -------------
__global__ __launch_bounds__(256) void agg2_kernel(
    const float* __restrict__ h2,
    const int* __restrict__ csr_rec_i, const float* __restrict__ w2csr,
    const int* __restrict__ rowptr,
    const float* __restrict__ b2, float* __restrict__ out, int N)
{
    int wave = (int)((blockIdx.x * blockDim.x + threadIdx.x) >> 6);
    if (wave >= N) return;
    int node = __builtin_amdgcn_readfirstlane(wave);
    int l = threadIdx.x & 63;
    int g = l >> 4, c = l & 15;
    int rs = rowptr[node], re = rowptr[node + 1];
    float acc = 0.f, sw = 0.f;
    int p = rs + g;
    for (; p + 4 < re; p += 8) {
        int sn0 = csr_rec_i[(size_t)p * 4];
        int sn1 = csr_rec_i[(size_t)(p + 4) * 4];
        float w0 = w2csr[p];
        float w1 = w2csr[p + 4];
        float x0 = h2[(size_t)sn0 * OUT2 + c];
        float x1 = h2[(size_t)sn1 * OUT2 + c];
        acc = fmaf(w0, x0, acc);
        acc = fmaf(w1, x1, acc);
        sw += w0 + w1;
    }
    if (p < re) {
        int sn = csr_rec_i[(size_t)p * 4];
        float w0 = w2csr[p];
        acc = fmaf(w0, h2[(size_t)sn * OUT2 + c], acc);
        sw += w0;
    }
    acc += __shfl_xor(acc, 16, 64);
    acc += __shfl_xor(acc, 32, 64);
    sw += __shfl_xor(sw, 16, 64);
    sw += __shfl_xor(sw, 32, 64);
    if (l < 16)
        out[(size_t)node * OUT2 + l] = acc / (sw + 1e-16f) + b2[l];
}

extern "C" void kernel_launch(void* const* d_in, const int* in_sizes, int n_in,
                              void* d_out, int out_size, void* d_ws, size_t ws_size,
                              hipStream_t stream)
{
    const float* x        = (const float*)d_in[0];
    const int*   ei       = (const int*)d_in[1];
    const float* W1       = (const float*)d_in[2];
    const float* att_src1 = (const float*)d_in[3];
    const float* att_dst1 = (const float*)d_in[4];
    const float* b1       = (const float*)d_in[5];
    const float* W2       = (const float*)d_in[6];
    const float* att_src2 = (const float*)d_in[7];
    const float* att_dst2 = (const float*)d_in[8];
    const float* b2       = (const float*)d_in[9];
    float* out = (float*)d_out;

    const int N = in_sizes[0] / FIN;
    const int E = in_sizes[1] / 2;
    const int* srcv = ei;
    const int* dstv = ei + E;

    char* base = (char*)d_ws;
    #define ALLOC(ptr, type, nelem) \
        type* ptr = (type*)base; base += (((size_t)(nelem) * sizeof(type) + 255) & ~(size_t)255);
    ALLOC(h1,      unsigned short, (size_t)N * HC)
    ALLOC(out1,    unsigned short, (size_t)N * HC)
    ALLOC(csr_rec, uint4,          (size_t)E)
    ALLOC(h2,      float,          (size_t)N * OUT2)
    ALLOC(a_src1v, float,          (size_t)N * 4)
    ALLOC(a_dst1v, float,          (size_t)N * 4)
    ALLOC(a_src2v, float,          (size_t)N)
    ALLOC(a_dst2v, float,          (size_t)N)
    ALLOC(counts,  int,            (size_t)2 * N)      // counts + cursor adjacent
    ALLOC(w2csr,   float,          (size_t)E)
    ALLOC(rowptr,  int,            (size_t)N + 1)
    ALLOC(bsum,    int,            1024)
    #undef ALLOC
    int* cursor = counts + N;
    // W1t (64 KB) aliases the head of csr_rec: live only between w1t_kernel and
    // gemm1_mfma_kernel; csr_rec is (re)written later by scatter_kernel.
    unsigned short* W1t = (unsigned short*)csr_rec;

    const int nb = (N + 1023) / 1024;

    (void)hipMemsetAsync(counts, 0, sizeof(int) * 2 * (size_t)N, stream);

    w1t_kernel<<<(HC * FIN + 255) / 256, 256, 0, stream>>>(W1, W1t);
    gemm1_mfma_kernel<<<(N + 63) / 64, 256, 0, stream>>>(x, W1t, h1, N);
    attdots1_kernel<<<(N + 3) / 4, 256, 0, stream>>>(h1, att_src1, att_dst1, a_src1v, a_dst1v, N);
    count_kernel<<<(E + 255) / 256, 256, 0, stream>>>(dstv, counts, E);
    scan1_kernel<<<nb, 1024, 0, stream>>>(counts, rowptr, bsum, N);
    scan2_kernel<<<1, 1024, 0, stream>>>(bsum, rowptr, nb, N, E);
    scan3_kernel<<<nb, 1024, 0, stream>>>(rowptr, bsum, N);
    scatter_kernel<<<(E + 255) / 256, 256, 0, stream>>>(srcv, dstv, rowptr, cursor,
                                                        a_src1v, a_dst1v, csr_rec, E);
    agg1_kernel<<<(N + 3) / 4, 256, 0, stream>>>(h1, csr_rec, rowptr, b1, out1, N);
    gemm2_kernel<<<(N + 15) / 16, 256, 0, stream>>>(out1, W2, att_src2, att_dst2, h2, a_src2v, a_dst2v, N);
    w2csr_kernel<<<(E + 255) / 256, 256, 0, stream>>>(csr_rec, a_src2v, a_dst2v, w2csr, E);
    agg2_kernel<<<(N + 3) / 4, 256, 0, stream>>>(h2, (const int*)csr_rec, w2csr, rowptr, b2, out, N);
}